// Round 11
// baseline (284.964 us; speedup 1.0000x reference)
//
#include <hip/hip_runtime.h>
#include <math.h>

#define BB   128   // batch
#define WW   128   // window
#define FIN  64
#define NNODE 64
#define NE   4096
#define EDIM 16
#define NH   4
#define CDIM 32
#define HC   128   // NH*CDIM
#define FLATD 8192
#define HIDD 2048

// ws layout (float offsets) — 6.3 MB total (was 10.5)
#define OFF_H    0u         // h[B][64][128]            1,048,576 f
#define OFF_XGB  1048576u   // xgat bf16 [B][8192] u16  = 524,288 f
#define OFF_ACC  1572864u   // fc2 accum [128][2]       = 256 f
#define OFF_BK   1573120u   // bucket ints: bstart[80] + blist[4096]

typedef unsigned short u16;
typedef u16      u16x8 __attribute__((ext_vector_type(8)));
typedef __bf16   bf16x8 __attribute__((ext_vector_type(8)));
typedef float    f32x4  __attribute__((ext_vector_type(4)));
typedef float    f32x16 __attribute__((ext_vector_type(16)));

__device__ __forceinline__ u16 f2bf(float f) {   // RNE fp32 -> bf16 bits
    unsigned u = __float_as_uint(f);
    u += 0x7fffu + ((u >> 16) & 1u);
    return (u16)(u >> 16);
}
__device__ __forceinline__ void hilo(float v, u16* h, u16* l) {
    u16 hh = f2bf(v);
    float hf = __uint_as_float(((unsigned)hh) << 16);
    *h = hh;
    *l = f2bf(v - hf);
}

// ---------------- K01: fused bucket-sort (block 256) + TCN/lin_l (blocks 0..255) -
// Conv LDS layout per r10 (conflict-free float4 reads). Bucket block also zeros
// the fc2 accumulator (k3 atomicAdds into it; stream order guarantees safety).
__global__ __launch_bounds__(256) void k01(
        const float* __restrict__ x, const float* __restrict__ tcn_w,
        const float* __restrict__ tcn_b, const float* __restrict__ lin_l_w,
        const float* __restrict__ lin_l_b, float* __restrict__ h,
        const int* __restrict__ ei, int* __restrict__ bstart,
        int* __restrict__ blist, float* __restrict__ accbuf)
{
    __shared__ float xsw[130*68];       // 34.6 KB, swizzled
    __shared__ float xg[32*132];
    __shared__ float twn[32*3*68];      // 25.5 KB
    __shared__ int cnt[64];
    __shared__ int cur[65];
    const int bid = blockIdx.x, t = threadIdx.x;

    if (bid == 256) {   // -------- bucket branch + acc zero --------
        accbuf[t] = 0.f;                 // 256 threads, 256 floats
        if (t < 64) cnt[t] = 0;
        __syncthreads();
        for (int e = t; e < NE; e += 256) atomicAdd(&cnt[ei[NE + e]], 1);
        __syncthreads();
        if (t == 0) {
            int run = 0;
            for (int n = 0; n < 64; ++n) { cur[n] = run; run += cnt[n]; }
            cur[64] = run;
        }
        __syncthreads();
        if (t < 65) bstart[t] = cur[t];
        __syncthreads();
        for (int e = t; e < NE; e += 256) {
            int d = ei[NE + e], s = ei[e];
            int p = atomicAdd(&cur[d], 1);
            blist[p] = (e << 12) | (d << 6) | s;
        }
        return;
    }

    const int b = bid >> 1, half = bid & 1;
    const int n0 = half * 32;

    // stage x (swizzled) and tcn_w (node-major, i-contiguous)
    for (int idx = t; idx < 8192; idx += 256) {
        const int wo = idx >> 6, i = idx & 63;
        const int row = wo + 1;
        const int g = (row >> 4) & 7;
        xsw[row*68 + (((i >> 2) ^ g) << 2) + (i & 3)] = x[b*8192 + idx];
    }
    for (int idx = t; idx < 6144; idx += 256) {
        const int nl = idx / 192, r = idx - nl*192;
        const int k = r >> 6, i = r & 63;
        twn[(nl*3 + k)*68 + i] = tcn_w[(n0 + nl)*192 + i*3 + k];
    }
    if (t < 68) { xsw[t] = 0.f; xsw[129*68 + t] = 0.f; }
    __syncthreads();

    {   // phase 1: conv — float4 over i, swizzled conflict-free reads
        const int nl = t >> 3;
        const int G  = t & 7;
        const int w0 = G * 16;
        float acc[16];
        const float tb = tcn_b[n0 + nl];
#pragma unroll
        for (int j = 0; j < 16; ++j) acc[j] = tb;
        for (int i4 = 0; i4 < 16; ++i4) {
            const float4 t0v = *(const float4*)&twn[(nl*3 + 0)*68 + i4*4];
            const float4 t1v = *(const float4*)&twn[(nl*3 + 1)*68 + i4*4];
            const float4 t2v = *(const float4*)&twn[(nl*3 + 2)*68 + i4*4];
            float4 r[18];
#pragma unroll
            for (int j = 0; j < 18; ++j) {
                const int gj = (G + (j >= 16 ? 1 : 0)) & 7;
                r[j] = *(const float4*)&xsw[(w0 + j)*68 + ((i4 ^ gj) << 2)];
            }
#pragma unroll
            for (int dw = 0; dw < 16; ++dw) {
                acc[dw] += r[dw+0].x*t0v.x + r[dw+0].y*t0v.y
                         + r[dw+0].z*t0v.z + r[dw+0].w*t0v.w
                         + r[dw+1].x*t1v.x + r[dw+1].y*t1v.y
                         + r[dw+1].z*t1v.z + r[dw+1].w*t1v.w
                         + r[dw+2].x*t2v.x + r[dw+2].y*t2v.y
                         + r[dw+2].z*t2v.z + r[dw+2].w*t2v.w;
            }
        }
#pragma unroll
        for (int dw = 0; dw < 16; ++dw) xg[nl*132 + w0 + dw] = acc[dw];
    }
    __syncthreads();

    {   // phase 2: 2 o x 8 n register tile
        const int o2 = t & 63, ng = t >> 6;
        const int oA = o2, oB = o2 + 64;
        float accA[8], accB[8];
        const float lbA = lin_l_b[oA], lbB = lin_l_b[oB];
#pragma unroll
        for (int j = 0; j < 8; ++j) { accA[j] = lbA; accB[j] = lbB; }
        for (int c = 0; c < 32; ++c) {
            const float4 lwA = *(const float4*)&lin_l_w[oA*128 + c*4];
            const float4 lwB = *(const float4*)&lin_l_w[oB*128 + c*4];
#pragma unroll
            for (int nn = 0; nn < 8; ++nn) {
                const float4 xv = *(const float4*)&xg[(ng*8+nn)*132 + c*4];
                accA[nn] += xv.x*lwA.x + xv.y*lwA.y + xv.z*lwA.z + xv.w*lwA.w;
                accB[nn] += xv.x*lwB.x + xv.y*lwB.y + xv.z*lwB.z + xv.w*lwB.w;
            }
        }
#pragma unroll
        for (int nn = 0; nn < 8; ++nn) {
            const int n = n0 + ng*8 + nn;
            h[(b*64 + n)*128 + oA] = accA[nn];
            h[(b*64 + n)*128 + oB] = accB[nn];
        }
    }
}

// ---------------- K2F: fused scores + softmax + P-build + P@H aggregation --------
// UNCHANGED (proven 44.5 us) — control.
#define CAPF 2560
__global__ __launch_bounds__(512, 1) void k2_fused(
        const float* __restrict__ hbase, const float* __restrict__ ea,
        const float* __restrict__ lin_e_w, const float* __restrict__ lin_e_b,
        const float* __restrict__ att, const int* __restrict__ bstart,
        const int* __restrict__ blist, u16* __restrict__ xgb)
{
    __shared__ float hbuf[64*132];
    __shared__ float scl[CAPF*4];
    __shared__ float Pm[4][32][68];
    __shared__ int   bst[33];
    const int b = blockIdx.x, half = blockIdx.y, t = threadIdx.x;
    const int lane = t & 63, wv = t >> 6, l32 = lane & 31, h5 = lane >> 5;

    const int lo  = bstart[half*32];
    const int cnt = min(bstart[half*32 + 32] - lo, CAPF);
    const int gcnt = (cnt + 31) >> 5;

    int g = wv;
    int pkc = 0; bool validc = false;
    float4 v0c = {0.f,0.f,0.f,0.f}, v1c = {0.f,0.f,0.f,0.f};
    if (g < gcnt) {
        const int idx0 = g*32 + l32;
        validc = idx0 < cnt;
        pkc = validc ? blist[lo + idx0] : 0;
        const float* eap = ea + ((size_t)b*NE + (size_t)(pkc >> 12))*16 + h5*8;
        v0c = *(const float4*)eap;
        v1c = *(const float4*)(eap + 4);
    }

    for (int idx = t; idx < 2048; idx += 512) {
        const int row = idx >> 5, c4 = (idx & 31) * 4;
        float4 hv = *(const float4*)&hbase[(size_t)b*8192 + row*128 + c4];
        const float4 eb = *(const float4*)&lin_e_b[c4];
        hv.x += 0.5f*eb.x; hv.y += 0.5f*eb.y;
        hv.z += 0.5f*eb.z; hv.w += 0.5f*eb.w;
        *(float4*)&hbuf[row*132 + c4] = hv;
    }
    {
        const f32x4 z4 = {0.f, 0.f, 0.f, 0.f};
        for (int idx = t; idx < 4*32*68/4; idx += 512) ((f32x4*)Pm)[idx] = z4;
    }
    if (t < 33) bst[t] = bstart[half*32 + t];
    bf16x8 Ah[4], Al[4];
#pragma unroll
    for (int mt = 0; mt < 4; ++mt) {
        const float* wp = &lin_e_w[(mt*32 + l32)*16 + h5*8];
        const float4 w0 = *(const float4*)wp;
        const float4 w1 = *(const float4*)(wp + 4);
        u16 th[8], tl[8];
        hilo(w0.x,&th[0],&tl[0]); hilo(w0.y,&th[1],&tl[1]);
        hilo(w0.z,&th[2],&tl[2]); hilo(w0.w,&th[3],&tl[3]);
        hilo(w1.x,&th[4],&tl[4]); hilo(w1.y,&th[5],&tl[5]);
        hilo(w1.z,&th[6],&tl[6]); hilo(w1.w,&th[7],&tl[7]);
        u16x8 vh = { th[0],th[1],th[2],th[3],th[4],th[5],th[6],th[7] };
        u16x8 vl = { tl[0],tl[1],tl[2],tl[3],tl[4],tl[5],tl[6],tl[7] };
        Ah[mt] = *(bf16x8*)&vh;
        Al[mt] = *(bf16x8*)&vl;
    }
    float4 attv[4][4];
#pragma unroll
    for (int mt = 0; mt < 4; ++mt)
#pragma unroll
        for (int gq = 0; gq < 4; ++gq)
            attv[mt][gq] = *(const float4*)&att[mt*32 + gq*8 + h5*4];
    __syncthreads();

    while (g < gcnt) {
        const int gn = g + 8;
        const int pk = pkc; const bool valid = validc;
        const float4 v0 = v0c, v1 = v1c;
        const int idx = g*32 + l32;
        if (gn < gcnt) {
            const int idxn = gn*32 + l32;
            validc = idxn < cnt;
            pkc = validc ? blist[lo + idxn] : 0;
            const float* eap = ea + ((size_t)b*NE + (size_t)(pkc >> 12))*16 + h5*8;
            v0c = *(const float4*)eap;
            v1c = *(const float4*)(eap + 4);
        } else {
            validc = false;
        }
        const int sn = pk & 63, dd = (pk >> 6) & 63;
        u16 bh[8], bl[8];
        hilo(v0.x,&bh[0],&bl[0]); hilo(v0.y,&bh[1],&bl[1]);
        hilo(v0.z,&bh[2],&bl[2]); hilo(v0.w,&bh[3],&bl[3]);
        hilo(v1.x,&bh[4],&bl[4]); hilo(v1.y,&bh[5],&bl[5]);
        hilo(v1.z,&bh[6],&bl[6]); hilo(v1.w,&bh[7],&bl[7]);
        u16x8 vbh = { bh[0],bh[1],bh[2],bh[3],bh[4],bh[5],bh[6],bh[7] };
        u16x8 vbl = { bl[0],bl[1],bl[2],bl[3],bl[4],bl[5],bl[6],bl[7] };
        const bf16x8 Bh = *(bf16x8*)&vbh;
        const bf16x8 Bl = *(bf16x8*)&vbl;
        float hacc[4];
#pragma unroll
        for (int mt = 0; mt < 4; ++mt) {
            f32x16 D = {0.f,0.f,0.f,0.f,0.f,0.f,0.f,0.f,
                        0.f,0.f,0.f,0.f,0.f,0.f,0.f,0.f};
            D = __builtin_amdgcn_mfma_f32_32x32x16_bf16(Al[mt], Bh, D, 0, 0, 0);
            D = __builtin_amdgcn_mfma_f32_32x32x16_bf16(Ah[mt], Bl, D, 0, 0, 0);
            D = __builtin_amdgcn_mfma_f32_32x32x16_bf16(Ah[mt], Bh, D, 0, 0, 0);
            float s = 0.f;
#pragma unroll
            for (int g4 = 0; g4 < 4; ++g4) {
                const int ob = mt*32 + g4*8 + h5*4;
                const float4 hd = *(const float4*)&hbuf[dd*132 + ob];
                const float4 hs = *(const float4*)&hbuf[sn*132 + ob];
                float x0 = hd.x + hs.x + D[g4*4+0];
                float x1 = hd.y + hs.y + D[g4*4+1];
                float x2 = hd.z + hs.z + D[g4*4+2];
                float x3 = hd.w + hs.w + D[g4*4+3];
                x0 = fmaxf(x0, 0.01f*x0); x1 = fmaxf(x1, 0.01f*x1);
                x2 = fmaxf(x2, 0.01f*x2); x3 = fmaxf(x3, 0.01f*x3);
                const float4 a4 = attv[mt][g4];
                s += a4.x*x0 + a4.y*x1 + a4.z*x2 + a4.w*x3;
            }
            hacc[mt] = s;
        }
#pragma unroll
        for (int hh = 0; hh < 4; ++hh)
            hacc[hh] += __shfl_xor(hacc[hh], 32);
        if (h5 == 0 && valid)
            *(float4*)&scl[idx*4] = make_float4(hacc[0], hacc[1], hacc[2], hacc[3]);
        g = gn;
    }
    __syncthreads();

    {
        const int pair = t >> 2, sub = t & 3;
        const int nl = pair >> 2, hh = pair & 3;
        const int s0 = bst[nl] - lo, s1 = bst[nl+1] - lo;
        float mx = -3.4e38f;
        for (int i = s0 + sub; i < s1; i += 4) mx = fmaxf(mx, scl[i*4 + hh]);
        mx = fmaxf(mx, __shfl_xor(mx, 1));
        mx = fmaxf(mx, __shfl_xor(mx, 2));
        float den = 0.f;
        for (int i = s0 + sub; i < s1; i += 4) {
            const float ex = __expf(scl[i*4 + hh] - mx);
            scl[i*4 + hh] = ex;
            den += ex;
        }
        den += __shfl_xor(den, 1);
        den += __shfl_xor(den, 2);
        const float rd = 1.0f / (den + 1e-16f);
        for (int i = s0 + sub; i < s1; i += 4) {
            const int src = blist[lo + i] & 63;
            atomicAdd(&Pm[hh][nl][src], scl[i*4 + hh] * rd);
        }
    }
    __syncthreads();

    {
        const int hh = wv >> 1, ct = wv & 1;
        const int l16 = lane & 15, q = lane >> 4;
        const int cb = hh*32 + ct*16 + l16;
        const float lb2 = 0.5f * lin_e_b[cb];
        bf16x8 Hh2[2], Hl2[2];
#pragma unroll
        for (int kk = 0; kk < 2; ++kk) {
            u16 hhv[8], hlv[8];
#pragma unroll
            for (int i = 0; i < 8; ++i) {
                const float v = hbuf[(kk*32 + q*8 + i)*132 + cb];
                hilo(v, &hhv[i], &hlv[i]);
            }
            u16x8 vhh = { hhv[0],hhv[1],hhv[2],hhv[3],hhv[4],hhv[5],hhv[6],hhv[7] };
            u16x8 vhl = { hlv[0],hlv[1],hlv[2],hlv[3],hlv[4],hlv[5],hlv[6],hlv[7] };
            Hh2[kk] = *(bf16x8*)&vhh;
            Hl2[kk] = *(bf16x8*)&vhl;
        }
#pragma unroll
        for (int mrow = 0; mrow < 32; mrow += 16) {
            f32x4 D = {0.f, 0.f, 0.f, 0.f};
#pragma unroll
            for (int kk = 0; kk < 2; ++kk) {
                const float* pp = &Pm[hh][mrow + l16][kk*32 + q*8];
                const float4 a0 = *(const float4*)pp;
                const float4 a1 = *(const float4*)(pp + 4);
                u16 ph[8], pl[8];
                hilo(a0.x,&ph[0],&pl[0]); hilo(a0.y,&ph[1],&pl[1]);
                hilo(a0.z,&ph[2],&pl[2]); hilo(a0.w,&ph[3],&pl[3]);
                hilo(a1.x,&ph[4],&pl[4]); hilo(a1.y,&ph[5],&pl[5]);
                hilo(a1.z,&ph[6],&pl[6]); hilo(a1.w,&ph[7],&pl[7]);
                u16x8 vph = { ph[0],ph[1],ph[2],ph[3],ph[4],ph[5],ph[6],ph[7] };
                u16x8 vpl = { pl[0],pl[1],pl[2],pl[3],pl[4],pl[5],pl[6],pl[7] };
                const bf16x8 Ph = *(bf16x8*)&vph, Pl = *(bf16x8*)&vpl;
                D = __builtin_amdgcn_mfma_f32_16x16x32_bf16(Pl, Hh2[kk], D, 0, 0, 0);
                D = __builtin_amdgcn_mfma_f32_16x16x32_bf16(Ph, Hl2[kk], D, 0, 0, 0);
                D = __builtin_amdgcn_mfma_f32_16x16x32_bf16(Ph, Hh2[kk], D, 0, 0, 0);
            }
#pragma unroll
            for (int r = 0; r < 4; ++r) {
                const int m = mrow + q*4 + r;
                const float corr = (bst[m+1] > bst[m]) ? lb2 : 0.f;
                float v = D[r] - corr;
                v = v > 0.f ? v : expm1f(v);
                xgb[(size_t)b*8192 + (half*32 + m)*128 + cb] = f2bf(v);
            }
        }
    }
}

// ---------------- K3F: fc1 + BN + relu + fc2 fused, full-K per block ------------
// grid 128 (j-tiles of 16), 512 thr = 8 waves (wave w owns m-rows w*16..w*16+15).
// Full K=8192 per block -> h1 complete in-register -> epilogue applies
// bias+BN+relu+fc2 and shfl-reduces over the 16 j-lanes; lane0 atomicAdds the
// per-row partial into accbuf[128][2] (zeroed by k01). Deletes the 4 MB part
// round-trip and k4's heavy pass. HBM floor: 64 MB fc1_w stream ~10 us.
#define KTOT 8192
__global__ __launch_bounds__(512) void k3_fc1(
        const u16* __restrict__ xgb, const float* __restrict__ fc1_w,
        const float* __restrict__ fc1_b, const float* __restrict__ bn_g,
        const float* __restrict__ bn_b, const float* __restrict__ fc2_w,
        float* __restrict__ accbuf)
{
    __shared__ u16 Ash[2][128*72];
    __shared__ u16 Bsh[2][16*72];
    const int jb = blockIdx.x, t = threadIdx.x;
    const int j0 = jb*16;
    const int wave = t >> 6, lane = t & 63;
    const int quad = lane >> 4, l16 = lane & 15;

    f32x4 acc = (f32x4){0.f, 0.f, 0.f, 0.f};

    const int arow = t >> 2, acol = (t & 3) * 16;   // A: 128 rows x 64, 16 el/thr
    const int brow = t >> 3, bcol = (t & 7) * 8;    // B: 16 rows x 64 (t<128)

#define K3_LOAD(KC, AR, B0, B1)                                               \
    {   const u16* ap = xgb + (size_t)arow*FLATD + (KC) + acol;               \
        AR[0] = *(const u16x8*)(ap); AR[1] = *(const u16x8*)(ap + 8);         \
        if (t < 128) {                                                        \
            const float* bp = fc1_w + (size_t)(j0 + brow)*FLATD + (KC) + bcol;\
            B0 = *(const float4*)bp; B1 = *(const float4*)(bp + 4);           \
        } }

#define K3_WRITE(BUF, AR, B0, B1)                                             \
    {   *(u16x8*)&Ash[BUF][arow*72 + acol]     = AR[0];                       \
        *(u16x8*)&Ash[BUF][arow*72 + acol + 8] = AR[1];                       \
        if (t < 128) {                                                        \
            u16x8 u = { f2bf(B0.x), f2bf(B0.y), f2bf(B0.z), f2bf(B0.w),       \
                        f2bf(B1.x), f2bf(B1.y), f2bf(B1.z), f2bf(B1.w) };     \
            *(u16x8*)&Bsh[BUF][brow*72 + bcol] = u;                           \
        } }

#define K3_MFMA(BUF)                                                          \
    {   _Pragma("unroll")                                                     \
        for (int kk = 0; kk < 64; kk += 32) {                                 \
            bf16x8 af = *(const bf16x8*)&Ash[BUF][(wave*16 + l16)*72 + kk + quad*8]; \
            bf16x8 bf = *(const bf16x8*)&Bsh[BUF][l16*72 + kk + quad*8];      \
            acc = __builtin_amdgcn_mfma_f32_16x16x32_bf16(af, bf, acc, 0, 0, 0); \
        } }

    u16x8 Ar0[2]; float4 B00 = {0,0,0,0}, B01 = {0,0,0,0};
    u16x8 Ar1[2]; float4 B10 = {0,0,0,0}, B11 = {0,0,0,0};

    K3_LOAD(0, Ar0, B00, B01);
    K3_WRITE(0, Ar0, B00, B01);
    K3_LOAD(64, Ar0, B00, B01);
    K3_LOAD(128, Ar1, B10, B11);
    __syncthreads();

    for (int kc = 0; kc < KTOT; kc += 128) {
        K3_MFMA(0);
        if (kc + 64 < KTOT)  K3_WRITE(1, Ar0, B00, B01);
        if (kc + 192 < KTOT) K3_LOAD(kc + 192, Ar0, B00, B01);
        __syncthreads();
        K3_MFMA(1);
        if (kc + 128 < KTOT) K3_WRITE(0, Ar1, B10, B11);
        if (kc + 256 < KTOT) K3_LOAD(kc + 256, Ar1, B10, B11);
        __syncthreads();
    }
#undef K3_LOAD
#undef K3_WRITE
#undef K3_MFMA

    // epilogue: bias + BN + relu + fc2, reduce over the 16 j-lanes
    {
        const float inv = 1.0f / sqrtf(1.0f + 1e-5f);
        const int n = j0 + l16;
        const float gj = bn_g[n] * inv, bj = bn_b[n], fj = fc1_b[n];
        const float w0 = fc2_w[n], w1 = fc2_w[2048 + n];
#pragma unroll
        for (int r = 0; r < 4; ++r) {
            float v = (acc[r] + fj) * gj + bj;
            v = fmaxf(v, 0.f);
            float q0 = v * w0, q1 = v * w1;
            q0 += __shfl_xor(q0, 1); q1 += __shfl_xor(q1, 1);
            q0 += __shfl_xor(q0, 2); q1 += __shfl_xor(q1, 2);
            q0 += __shfl_xor(q0, 4); q1 += __shfl_xor(q1, 4);
            q0 += __shfl_xor(q0, 8); q1 += __shfl_xor(q1, 8);
            if (l16 == 0) {
                const int m = wave*16 + quad*4 + r;     // batch row
                atomicAdd(&accbuf[m*2 + 0], q0);
                atomicAdd(&accbuf[m*2 + 1], q1);
            }
        }
    }
}

// ---------------- K4: micro epilogue — add fc2 bias, write out ------------------
__global__ __launch_bounds__(256) void k4_out(
        const float* __restrict__ accbuf, const float* __restrict__ fc2_b,
        float* __restrict__ out)
{
    const int t = threadIdx.x;      // 256 = 128 batches x 2 logits
    out[t] = accbuf[t] + fc2_b[t & 1];
}

extern "C" void kernel_launch(void* const* d_in, const int* in_sizes, int n_in,
                              void* d_out, int out_size, void* d_ws, size_t ws_size,
                              hipStream_t stream)
{
    const float* x       = (const float*)d_in[0];
    const int*   ei      = (const int*)  d_in[1];
    const float* ea      = (const float*)d_in[2];
    const float* tcn_w   = (const float*)d_in[3];
    const float* tcn_b   = (const float*)d_in[4];
    const float* lin_l_w = (const float*)d_in[5];
    const float* lin_l_b = (const float*)d_in[6];
    const float* lin_e_w = (const float*)d_in[7];
    const float* lin_e_b = (const float*)d_in[8];
    const float* att     = (const float*)d_in[9];
    const float* fc1_w   = (const float*)d_in[10];
    const float* fc1_b   = (const float*)d_in[11];
    const float* bn_g    = (const float*)d_in[12];
    const float* bn_b    = (const float*)d_in[13];
    const float* fc2_w   = (const float*)d_in[14];
    const float* fc2_b   = (const float*)d_in[15];

    float* ws     = (float*)d_ws;
    float* hbuf   = ws + OFF_H;
    u16*   xgb    = (u16*)(ws + OFF_XGB);
    float* accbuf = ws + OFF_ACC;
    int*   bstart = (int*)(ws + OFF_BK);
    int*   blist  = bstart + 80;
    float* out    = (float*)d_out;

    k01     <<<257, 256, 0, stream>>>(x, tcn_w, tcn_b, lin_l_w, lin_l_b, hbuf,
                                      ei, bstart, blist, accbuf);
    k2_fused<<<dim3(BB, 2), 512, 0, stream>>>(hbuf, ea, lin_e_w, lin_e_b, att,
                                              bstart, blist, xgb);
    k3_fc1  <<<128, 512, 0, stream>>>(xgb, fc1_w, fc1_b, bn_g, bn_b, fc2_w,
                                      accbuf);
    k4_out  <<<1, 256, 0, stream>>>(accbuf, fc2_b, out);
}

// Round 12
// 221.640 us; speedup vs baseline: 1.2857x; 1.2857x over previous
//
#include <hip/hip_runtime.h>
#include <math.h>

#define BB   128   // batch
#define WW   128   // window
#define FIN  64
#define NNODE 64
#define NE   4096
#define EDIM 16
#define NH   4
#define CDIM 32
#define HC   128   // NH*CDIM
#define FLATD 8192
#define HIDD 2048

// ws layout (float offsets) — repacked, 10.5 MB total
#define OFF_H    0u         // h[B][64][128]            1,048,576 f
#define OFF_P    1048576u   // fc1 partials [4][128][2048] = 1,048,576 f
#define OFF_XGB  2097152u   // xgat bf16 [B][8192] u16  = 524,288 f
#define OFF_BK   2621440u   // bucket ints: bstart[80] + blist[4096]

typedef unsigned short u16;
typedef u16      u16x8 __attribute__((ext_vector_type(8)));
typedef __bf16   bf16x8 __attribute__((ext_vector_type(8)));
typedef float    f32x4  __attribute__((ext_vector_type(4)));
typedef float    f32x16 __attribute__((ext_vector_type(16)));

__device__ __forceinline__ u16 f2bf(float f) {   // RNE fp32 -> bf16 bits
    unsigned u = __float_as_uint(f);
    u += 0x7fffu + ((u >> 16) & 1u);
    return (u16)(u >> 16);
}
__device__ __forceinline__ void hilo(float v, u16* h, u16* l) {
    u16 hh = f2bf(v);
    float hf = __uint_as_float(((unsigned)hh) << 16);
    *h = hh;
    *l = f2bf(v - hf);
}

// ---------------- K01: fused bucket-sort (block 256) + TCN/lin_l (blocks 0..255) -
// Conv LDS fix (r9 counters: 15.6M conflicts from scalar xs reads):
//  - xs rows stride 68, chunk-XOR swizzle: chunk(w,i4) = i4 ^ ((w>>4)&7).
//  - weights as twn[nl][k][i] (i-contiguous float4).
__global__ __launch_bounds__(256) void k01(
        const float* __restrict__ x, const float* __restrict__ tcn_w,
        const float* __restrict__ tcn_b, const float* __restrict__ lin_l_w,
        const float* __restrict__ lin_l_b, float* __restrict__ h,
        const int* __restrict__ ei, int* __restrict__ bstart,
        int* __restrict__ blist)
{
    __shared__ float xsw[130*68];       // 34.6 KB, swizzled
    __shared__ float xg[32*132];
    __shared__ float twn[32*3*68];      // 25.5 KB
    __shared__ int cnt[64];
    __shared__ int cur[65];
    const int bid = blockIdx.x, t = threadIdx.x;

    if (bid == 256) {   // -------- bucket branch --------
        if (t < 64) cnt[t] = 0;
        __syncthreads();
        for (int e = t; e < NE; e += 256) atomicAdd(&cnt[ei[NE + e]], 1);
        __syncthreads();
        if (t == 0) {
            int run = 0;
            for (int n = 0; n < 64; ++n) { cur[n] = run; run += cnt[n]; }
            cur[64] = run;
        }
        __syncthreads();
        if (t < 65) bstart[t] = cur[t];
        __syncthreads();
        for (int e = t; e < NE; e += 256) {
            int d = ei[NE + e], s = ei[e];
            int p = atomicAdd(&cur[d], 1);
            blist[p] = (e << 12) | (d << 6) | s;
        }
        return;
    }

    const int b = bid >> 1, half = bid & 1;
    const int n0 = half * 32;

    // stage x (swizzled) and tcn_w (node-major, i-contiguous)
    for (int idx = t; idx < 8192; idx += 256) {
        const int wo = idx >> 6, i = idx & 63;
        const int row = wo + 1;
        const int g = (row >> 4) & 7;
        xsw[row*68 + (((i >> 2) ^ g) << 2) + (i & 3)] = x[b*8192 + idx];
    }
    for (int idx = t; idx < 6144; idx += 256) {
        const int nl = idx / 192, r = idx - nl*192;
        const int k = r >> 6, i = r & 63;
        twn[(nl*3 + k)*68 + i] = tcn_w[(n0 + nl)*192 + i*3 + k];
    }
    if (t < 68) { xsw[t] = 0.f; xsw[129*68 + t] = 0.f; }
    __syncthreads();

    {   // phase 1: conv — float4 over i, swizzled conflict-free reads
        const int nl = t >> 3;
        const int G  = t & 7;
        const int w0 = G * 16;
        float acc[16];
        const float tb = tcn_b[n0 + nl];
#pragma unroll
        for (int j = 0; j < 16; ++j) acc[j] = tb;
        for (int i4 = 0; i4 < 16; ++i4) {
            const float4 t0v = *(const float4*)&twn[(nl*3 + 0)*68 + i4*4];
            const float4 t1v = *(const float4*)&twn[(nl*3 + 1)*68 + i4*4];
            const float4 t2v = *(const float4*)&twn[(nl*3 + 2)*68 + i4*4];
            float4 r[18];
#pragma unroll
            for (int j = 0; j < 18; ++j) {
                const int gj = (G + (j >= 16 ? 1 : 0)) & 7;
                r[j] = *(const float4*)&xsw[(w0 + j)*68 + ((i4 ^ gj) << 2)];
            }
#pragma unroll
            for (int dw = 0; dw < 16; ++dw) {
                acc[dw] += r[dw+0].x*t0v.x + r[dw+0].y*t0v.y
                         + r[dw+0].z*t0v.z + r[dw+0].w*t0v.w
                         + r[dw+1].x*t1v.x + r[dw+1].y*t1v.y
                         + r[dw+1].z*t1v.z + r[dw+1].w*t1v.w
                         + r[dw+2].x*t2v.x + r[dw+2].y*t2v.y
                         + r[dw+2].z*t2v.z + r[dw+2].w*t2v.w;
            }
        }
#pragma unroll
        for (int dw = 0; dw < 16; ++dw) xg[nl*132 + w0 + dw] = acc[dw];
    }
    __syncthreads();

    {   // phase 2: 2 o x 8 n register tile
        const int o2 = t & 63, ng = t >> 6;
        const int oA = o2, oB = o2 + 64;
        float accA[8], accB[8];
        const float lbA = lin_l_b[oA], lbB = lin_l_b[oB];
#pragma unroll
        for (int j = 0; j < 8; ++j) { accA[j] = lbA; accB[j] = lbB; }
        for (int c = 0; c < 32; ++c) {
            const float4 lwA = *(const float4*)&lin_l_w[oA*128 + c*4];
            const float4 lwB = *(const float4*)&lin_l_w[oB*128 + c*4];
#pragma unroll
            for (int nn = 0; nn < 8; ++nn) {
                const float4 xv = *(const float4*)&xg[(ng*8+nn)*132 + c*4];
                accA[nn] += xv.x*lwA.x + xv.y*lwA.y + xv.z*lwA.z + xv.w*lwA.w;
                accB[nn] += xv.x*lwB.x + xv.y*lwB.y + xv.z*lwB.z + xv.w*lwB.w;
            }
        }
#pragma unroll
        for (int nn = 0; nn < 8; ++nn) {
            const int n = n0 + ng*8 + nn;
            h[(b*64 + n)*128 + oA] = accA[nn];
            h[(b*64 + n)*128 + oB] = accB[nn];
        }
    }
}

// ---------------- K2F: fused scores + softmax + P-build + P@H aggregation --------
// UNCHANGED (proven 44.5 us) — control.
#define CAPF 2560
__global__ __launch_bounds__(512, 1) void k2_fused(
        const float* __restrict__ hbase, const float* __restrict__ ea,
        const float* __restrict__ lin_e_w, const float* __restrict__ lin_e_b,
        const float* __restrict__ att, const int* __restrict__ bstart,
        const int* __restrict__ blist, u16* __restrict__ xgb)
{
    __shared__ float hbuf[64*132];
    __shared__ float scl[CAPF*4];
    __shared__ float Pm[4][32][68];
    __shared__ int   bst[33];
    const int b = blockIdx.x, half = blockIdx.y, t = threadIdx.x;
    const int lane = t & 63, wv = t >> 6, l32 = lane & 31, h5 = lane >> 5;

    const int lo  = bstart[half*32];
    const int cnt = min(bstart[half*32 + 32] - lo, CAPF);
    const int gcnt = (cnt + 31) >> 5;

    int g = wv;
    int pkc = 0; bool validc = false;
    float4 v0c = {0.f,0.f,0.f,0.f}, v1c = {0.f,0.f,0.f,0.f};
    if (g < gcnt) {
        const int idx0 = g*32 + l32;
        validc = idx0 < cnt;
        pkc = validc ? blist[lo + idx0] : 0;
        const float* eap = ea + ((size_t)b*NE + (size_t)(pkc >> 12))*16 + h5*8;
        v0c = *(const float4*)eap;
        v1c = *(const float4*)(eap + 4);
    }

    for (int idx = t; idx < 2048; idx += 512) {
        const int row = idx >> 5, c4 = (idx & 31) * 4;
        float4 hv = *(const float4*)&hbase[(size_t)b*8192 + row*128 + c4];
        const float4 eb = *(const float4*)&lin_e_b[c4];
        hv.x += 0.5f*eb.x; hv.y += 0.5f*eb.y;
        hv.z += 0.5f*eb.z; hv.w += 0.5f*eb.w;
        *(float4*)&hbuf[row*132 + c4] = hv;
    }
    {
        const f32x4 z4 = {0.f, 0.f, 0.f, 0.f};
        for (int idx = t; idx < 4*32*68/4; idx += 512) ((f32x4*)Pm)[idx] = z4;
    }
    if (t < 33) bst[t] = bstart[half*32 + t];
    bf16x8 Ah[4], Al[4];
#pragma unroll
    for (int mt = 0; mt < 4; ++mt) {
        const float* wp = &lin_e_w[(mt*32 + l32)*16 + h5*8];
        const float4 w0 = *(const float4*)wp;
        const float4 w1 = *(const float4*)(wp + 4);
        u16 th[8], tl[8];
        hilo(w0.x,&th[0],&tl[0]); hilo(w0.y,&th[1],&tl[1]);
        hilo(w0.z,&th[2],&tl[2]); hilo(w0.w,&th[3],&tl[3]);
        hilo(w1.x,&th[4],&tl[4]); hilo(w1.y,&th[5],&tl[5]);
        hilo(w1.z,&th[6],&tl[6]); hilo(w1.w,&th[7],&tl[7]);
        u16x8 vh = { th[0],th[1],th[2],th[3],th[4],th[5],th[6],th[7] };
        u16x8 vl = { tl[0],tl[1],tl[2],tl[3],tl[4],tl[5],tl[6],tl[7] };
        Ah[mt] = *(bf16x8*)&vh;
        Al[mt] = *(bf16x8*)&vl;
    }
    float4 attv[4][4];
#pragma unroll
    for (int mt = 0; mt < 4; ++mt)
#pragma unroll
        for (int gq = 0; gq < 4; ++gq)
            attv[mt][gq] = *(const float4*)&att[mt*32 + gq*8 + h5*4];
    __syncthreads();

    while (g < gcnt) {
        const int gn = g + 8;
        const int pk = pkc; const bool valid = validc;
        const float4 v0 = v0c, v1 = v1c;
        const int idx = g*32 + l32;
        if (gn < gcnt) {
            const int idxn = gn*32 + l32;
            validc = idxn < cnt;
            pkc = validc ? blist[lo + idxn] : 0;
            const float* eap = ea + ((size_t)b*NE + (size_t)(pkc >> 12))*16 + h5*8;
            v0c = *(const float4*)eap;
            v1c = *(const float4*)(eap + 4);
        } else {
            validc = false;
        }
        const int sn = pk & 63, dd = (pk >> 6) & 63;
        u16 bh[8], bl[8];
        hilo(v0.x,&bh[0],&bl[0]); hilo(v0.y,&bh[1],&bl[1]);
        hilo(v0.z,&bh[2],&bl[2]); hilo(v0.w,&bh[3],&bl[3]);
        hilo(v1.x,&bh[4],&bl[4]); hilo(v1.y,&bh[5],&bl[5]);
        hilo(v1.z,&bh[6],&bl[6]); hilo(v1.w,&bh[7],&bl[7]);
        u16x8 vbh = { bh[0],bh[1],bh[2],bh[3],bh[4],bh[5],bh[6],bh[7] };
        u16x8 vbl = { bl[0],bl[1],bl[2],bl[3],bl[4],bl[5],bl[6],bl[7] };
        const bf16x8 Bh = *(bf16x8*)&vbh;
        const bf16x8 Bl = *(bf16x8*)&vbl;
        float hacc[4];
#pragma unroll
        for (int mt = 0; mt < 4; ++mt) {
            f32x16 D = {0.f,0.f,0.f,0.f,0.f,0.f,0.f,0.f,
                        0.f,0.f,0.f,0.f,0.f,0.f,0.f,0.f};
            D = __builtin_amdgcn_mfma_f32_32x32x16_bf16(Al[mt], Bh, D, 0, 0, 0);
            D = __builtin_amdgcn_mfma_f32_32x32x16_bf16(Ah[mt], Bl, D, 0, 0, 0);
            D = __builtin_amdgcn_mfma_f32_32x32x16_bf16(Ah[mt], Bh, D, 0, 0, 0);
            float s = 0.f;
#pragma unroll
            for (int g4 = 0; g4 < 4; ++g4) {
                const int ob = mt*32 + g4*8 + h5*4;
                const float4 hd = *(const float4*)&hbuf[dd*132 + ob];
                const float4 hs = *(const float4*)&hbuf[sn*132 + ob];
                float x0 = hd.x + hs.x + D[g4*4+0];
                float x1 = hd.y + hs.y + D[g4*4+1];
                float x2 = hd.z + hs.z + D[g4*4+2];
                float x3 = hd.w + hs.w + D[g4*4+3];
                x0 = fmaxf(x0, 0.01f*x0); x1 = fmaxf(x1, 0.01f*x1);
                x2 = fmaxf(x2, 0.01f*x2); x3 = fmaxf(x3, 0.01f*x3);
                const float4 a4 = attv[mt][g4];
                s += a4.x*x0 + a4.y*x1 + a4.z*x2 + a4.w*x3;
            }
            hacc[mt] = s;
        }
#pragma unroll
        for (int hh = 0; hh < 4; ++hh)
            hacc[hh] += __shfl_xor(hacc[hh], 32);
        if (h5 == 0 && valid)
            *(float4*)&scl[idx*4] = make_float4(hacc[0], hacc[1], hacc[2], hacc[3]);
        g = gn;
    }
    __syncthreads();

    {
        const int pair = t >> 2, sub = t & 3;
        const int nl = pair >> 2, hh = pair & 3;
        const int s0 = bst[nl] - lo, s1 = bst[nl+1] - lo;
        float mx = -3.4e38f;
        for (int i = s0 + sub; i < s1; i += 4) mx = fmaxf(mx, scl[i*4 + hh]);
        mx = fmaxf(mx, __shfl_xor(mx, 1));
        mx = fmaxf(mx, __shfl_xor(mx, 2));
        float den = 0.f;
        for (int i = s0 + sub; i < s1; i += 4) {
            const float ex = __expf(scl[i*4 + hh] - mx);
            scl[i*4 + hh] = ex;
            den += ex;
        }
        den += __shfl_xor(den, 1);
        den += __shfl_xor(den, 2);
        const float rd = 1.0f / (den + 1e-16f);
        for (int i = s0 + sub; i < s1; i += 4) {
            const int src = blist[lo + i] & 63;
            atomicAdd(&Pm[hh][nl][src], scl[i*4 + hh] * rd);
        }
    }
    __syncthreads();

    {
        const int hh = wv >> 1, ct = wv & 1;
        const int l16 = lane & 15, q = lane >> 4;
        const int cb = hh*32 + ct*16 + l16;
        const float lb2 = 0.5f * lin_e_b[cb];
        bf16x8 Hh2[2], Hl2[2];
#pragma unroll
        for (int kk = 0; kk < 2; ++kk) {
            u16 hhv[8], hlv[8];
#pragma unroll
            for (int i = 0; i < 8; ++i) {
                const float v = hbuf[(kk*32 + q*8 + i)*132 + cb];
                hilo(v, &hhv[i], &hlv[i]);
            }
            u16x8 vhh = { hhv[0],hhv[1],hhv[2],hhv[3],hhv[4],hhv[5],hhv[6],hhv[7] };
            u16x8 vhl = { hlv[0],hlv[1],hlv[2],hlv[3],hlv[4],hlv[5],hlv[6],hlv[7] };
            Hh2[kk] = *(bf16x8*)&vhh;
            Hl2[kk] = *(bf16x8*)&vhl;
        }
#pragma unroll
        for (int mrow = 0; mrow < 32; mrow += 16) {
            f32x4 D = {0.f, 0.f, 0.f, 0.f};
#pragma unroll
            for (int kk = 0; kk < 2; ++kk) {
                const float* pp = &Pm[hh][mrow + l16][kk*32 + q*8];
                const float4 a0 = *(const float4*)pp;
                const float4 a1 = *(const float4*)(pp + 4);
                u16 ph[8], pl[8];
                hilo(a0.x,&ph[0],&pl[0]); hilo(a0.y,&ph[1],&pl[1]);
                hilo(a0.z,&ph[2],&pl[2]); hilo(a0.w,&ph[3],&pl[3]);
                hilo(a1.x,&ph[4],&pl[4]); hilo(a1.y,&ph[5],&pl[5]);
                hilo(a1.z,&ph[6],&pl[6]); hilo(a1.w,&ph[7],&pl[7]);
                u16x8 vph = { ph[0],ph[1],ph[2],ph[3],ph[4],ph[5],ph[6],ph[7] };
                u16x8 vpl = { pl[0],pl[1],pl[2],pl[3],pl[4],pl[5],pl[6],pl[7] };
                const bf16x8 Ph = *(bf16x8*)&vph, Pl = *(bf16x8*)&vpl;
                D = __builtin_amdgcn_mfma_f32_16x16x32_bf16(Pl, Hh2[kk], D, 0, 0, 0);
                D = __builtin_amdgcn_mfma_f32_16x16x32_bf16(Ph, Hl2[kk], D, 0, 0, 0);
                D = __builtin_amdgcn_mfma_f32_16x16x32_bf16(Ph, Hh2[kk], D, 0, 0, 0);
            }
#pragma unroll
            for (int r = 0; r < 4; ++r) {
                const int m = mrow + q*4 + r;
                const float corr = (bst[m+1] > bst[m]) ? lb2 : 0.f;
                float v = D[r] - corr;
                v = v > 0.f ? v : expm1f(v);
                xgb[(size_t)b*8192 + (half*32 + m)*128 + cb] = f2bf(v);
            }
        }
    }
}

// ---------------- K3: fc1 bf16 MFMA; double-buffer; split-K 4 (256 blocks=1/CU) --
#define KTOT 2048
__global__ __launch_bounds__(256) void k3_fc1(
        const u16* __restrict__ xgb, const float* __restrict__ fc1_w,
        float* __restrict__ part)
{
    __shared__ u16 Ash[2][128*72];
    __shared__ u16 Bsh[2][32*72];
    const int jb = blockIdx.x, ks = blockIdx.y, t = threadIdx.x;
    const int j0 = jb*32, k0 = ks*KTOT;
    const int wave = t >> 6, lane = t & 63;
    const int quad = lane >> 4, l16 = lane & 15;
    const int wm = (wave & 1) * 64, wn = (wave >> 1) * 16;

    f32x4 acc[4];
#pragma unroll
    for (int i = 0; i < 4; ++i) acc[i] = (f32x4){0.f, 0.f, 0.f, 0.f};

    const int arow = t >> 1, acol = (t & 1) * 32;
    const int brow = t >> 3, bcol = (t & 7) * 8;

#define K3_LOAD(KC, AR, B0, B1)                                              \
    {   const u16* ap = xgb + (size_t)arow*FLATD + k0 + (KC) + acol;         \
        AR[0] = *(const u16x8*)(ap);      AR[1] = *(const u16x8*)(ap + 8);   \
        AR[2] = *(const u16x8*)(ap + 16); AR[3] = *(const u16x8*)(ap + 24);  \
        const float* bp = fc1_w + (size_t)(j0 + brow)*FLATD + k0 + (KC) + bcol; \
        B0 = *(const float4*)bp; B1 = *(const float4*)(bp + 4); }

#define K3_WRITE(BUF, AR, B0, B1)                                            \
    {   *(u16x8*)&Ash[BUF][arow*72 + acol]      = AR[0];                     \
        *(u16x8*)&Ash[BUF][arow*72 + acol + 8]  = AR[1];                     \
        *(u16x8*)&Ash[BUF][arow*72 + acol + 16] = AR[2];                     \
        *(u16x8*)&Ash[BUF][arow*72 + acol + 24] = AR[3];                     \
        u16x8 u = { f2bf(B0.x), f2bf(B0.y), f2bf(B0.z), f2bf(B0.w),          \
                    f2bf(B1.x), f2bf(B1.y), f2bf(B1.z), f2bf(B1.w) };        \
        *(u16x8*)&Bsh[BUF][brow*72 + bcol] = u; }

#define K3_MFMA(BUF)                                                         \
    {   _Pragma("unroll")                                                    \
        for (int kk = 0; kk < 64; kk += 32) {                                \
            bf16x8 af[4], bfr;                                               \
            _Pragma("unroll")                                                \
            for (int i = 0; i < 4; ++i)                                      \
                af[i] = *(const bf16x8*)&Ash[BUF][(wm + i*16 + l16)*72 + kk + quad*8]; \
            bfr = *(const bf16x8*)&Bsh[BUF][(wn + l16)*72 + kk + quad*8];    \
            _Pragma("unroll")                                                \
            for (int i = 0; i < 4; ++i)                                      \
                acc[i] = __builtin_amdgcn_mfma_f32_16x16x32_bf16(af[i], bfr, acc[i], 0, 0, 0); \
        } }

    u16x8 Ar0[4]; float4 B00, B01;
    u16x8 Ar1[4]; float4 B10, B11;

    K3_LOAD(0, Ar0, B00, B01);
    K3_WRITE(0, Ar0, B00, B01);
    K3_LOAD(64, Ar0, B00, B01);
    K3_LOAD(128, Ar1, B10, B11);
    __syncthreads();

    for (int kc = 0; kc < KTOT; kc += 128) {
        K3_MFMA(0);
        if (kc + 64 < KTOT)  K3_WRITE(1, Ar0, B00, B01);
        if (kc + 192 < KTOT) K3_LOAD(kc + 192, Ar0, B00, B01);
        __syncthreads();
        K3_MFMA(1);
        if (kc + 128 < KTOT) K3_WRITE(0, Ar1, B10, B11);
        if (kc + 256 < KTOT) K3_LOAD(kc + 256, Ar1, B10, B11);
        __syncthreads();
    }
#undef K3_LOAD
#undef K3_WRITE
#undef K3_MFMA

#pragma unroll
    for (int i = 0; i < 4; ++i) {
        const int n = j0 + wn + l16;
#pragma unroll
        for (int r = 0; r < 4; ++r) {
            const int m = wm + i*16 + quad*4 + r;
            part[(size_t)ks*262144 + (size_t)m*HIDD + n] = acc[i][r];
        }
    }
}

// ---------------- K4: reduce partials + bias + BN + relu + fc2 ----------------
__global__ __launch_bounds__(1024) void k4_fc2(
        const float* __restrict__ part, const float* __restrict__ fc1_b,
        const float* __restrict__ bn_g, const float* __restrict__ bn_b,
        const float* __restrict__ fc2_w, const float* __restrict__ fc2_b,
        float* __restrict__ out)
{
    __shared__ float w0s[16], w1s[16];
    const int b = blockIdx.x, t = threadIdx.x;
    const int lane = t & 63, wv = t >> 6;
    const float inv = 1.0f / sqrtf(1.0f + 1e-5f);
    float p0 = 0.f, p1 = 0.f;
#pragma unroll
    for (int jj = 0; jj < 2; ++jj) {
        const int j = t + jj*1024;
        float hv = 0.f;
#pragma unroll
        for (int s = 0; s < 4; ++s) hv += part[(size_t)s*262144 + (size_t)b*2048 + j];
        float v = (hv + fc1_b[j]) * (bn_g[j] * inv) + bn_b[j];
        v = fmaxf(v, 0.f);
        p0 += v * fc2_w[j];
        p1 += v * fc2_w[2048 + j];
    }
#pragma unroll
    for (int d = 1; d < 64; d <<= 1) {
        p0 += __shfl_xor(p0, d);
        p1 += __shfl_xor(p1, d);
    }
    if (lane == 0) { w0s[wv] = p0; w1s[wv] = p1; }
    __syncthreads();
    if (t == 0) {
        float s0 = 0.f, s1 = 0.f;
#pragma unroll
        for (int i = 0; i < 16; ++i) { s0 += w0s[i]; s1 += w1s[i]; }
        out[b*2 + 0] = s0 + fc2_b[0];
        out[b*2 + 1] = s1 + fc2_b[1];
    }
}

extern "C" void kernel_launch(void* const* d_in, const int* in_sizes, int n_in,
                              void* d_out, int out_size, void* d_ws, size_t ws_size,
                              hipStream_t stream)
{
    const float* x       = (const float*)d_in[0];
    const int*   ei      = (const int*)  d_in[1];
    const float* ea      = (const float*)d_in[2];
    const float* tcn_w   = (const float*)d_in[3];
    const float* tcn_b   = (const float*)d_in[4];
    const float* lin_l_w = (const float*)d_in[5];
    const float* lin_l_b = (const float*)d_in[6];
    const float* lin_e_w = (const float*)d_in[7];
    const float* lin_e_b = (const float*)d_in[8];
    const float* att     = (const float*)d_in[9];
    const float* fc1_w   = (const float*)d_in[10];
    const float* fc1_b   = (const float*)d_in[11];
    const float* bn_g    = (const float*)d_in[12];
    const float* bn_b    = (const float*)d_in[13];
    const float* fc2_w   = (const float*)d_in[14];
    const float* fc2_b   = (const float*)d_in[15];

    float* ws     = (float*)d_ws;
    float* hbuf   = ws + OFF_H;
    float* part   = ws + OFF_P;
    u16*   xgb    = (u16*)(ws + OFF_XGB);
    int*   bstart = (int*)(ws + OFF_BK);
    int*   blist  = bstart + 80;
    float* out    = (float*)d_out;

    k01     <<<257, 256, 0, stream>>>(x, tcn_w, tcn_b, lin_l_w, lin_l_b, hbuf,
                                      ei, bstart, blist);
    k2_fused<<<dim3(BB, 2), 512, 0, stream>>>(hbuf, ea, lin_e_w, lin_e_b, att,
                                              bstart, blist, xgb);
    k3_fc1  <<<dim3(64, 4), 256, 0, stream>>>(xgb, fc1_w, part);
    k4_fc2  <<<BB, 1024, 0, stream>>>(part, fc1_b, bn_g, bn_b, fc2_w, fc2_b, out);
}